// Round 3
// baseline (691.451 us; speedup 1.0000x reference)
//
#include <hip/hip_runtime.h>
#include <hip/hip_bf16.h>
#include <stdint.h>

typedef unsigned short u16;
typedef __attribute__((ext_vector_type(8))) short short8;
typedef __attribute__((ext_vector_type(8))) unsigned short u16x8;
typedef __attribute__((ext_vector_type(4))) float f32x4;

#define B_    2
#define S_    2048
#define H_    32
#define HKV_  8
#define D_    128
#define HID_  4096
#define QKVW_ 6144

__device__ __forceinline__ u16 f2bf(float f){
  uint32_t b = __builtin_bit_cast(uint32_t, f);
  b += 0x7FFFu + ((b >> 16) & 1u);
  return (u16)(b >> 16);
}
__device__ __forceinline__ float bf2f(u16 h){
  uint32_t b = ((uint32_t)h) << 16;
  return __builtin_bit_cast(float, b);
}
__device__ __forceinline__ u16 bfc(float f){
  __hip_bfloat16 h = __float2bfloat16(f);
  return __builtin_bit_cast(u16, h);
}

__device__ __forceinline__ void gload16(const u16* g, u16* l){
  __builtin_amdgcn_global_load_lds((const __attribute__((address_space(1))) void*)g,
                                   (__attribute__((address_space(3))) void*)l, 16, 0, 0);
}

// ---------------- fp32 -> bf16 convert ----------------
__global__ void cvt_kernel(const float* __restrict__ src, u16* __restrict__ dst, int n4){
  int i = blockIdx.x * blockDim.x + threadIdx.x;
  int stride = gridDim.x * blockDim.x;
  for (; i < n4; i += stride){
    float4 v = reinterpret_cast<const float4*>(src)[i];
    union { u16 u[4]; unsigned long long ll; } o;
    o.u[0] = f2bf(v.x); o.u[1] = f2bf(v.y); o.u[2] = f2bf(v.z); o.u[3] = f2bf(v.w);
    reinterpret_cast<unsigned long long*>(dst)[i] = o.ll;
  }
}

// ---------------- RoPE table ----------------
__global__ void rope_table_kernel(float2* __restrict__ tab){
  int idx = blockIdx.x * blockDim.x + threadIdx.x;
  if (idx >= S_ * 64) return;
  int pos = idx >> 6, p = idx & 63;
  float inv = powf(10000.0f, -(float)p / 64.0f);
  float ang = (float)pos * inv;
  tab[idx] = make_float2(cosf(ang), sinf(ang));
}

// ---------------- RoPE apply ----------------
__global__ void rope_apply_kernel(u16* __restrict__ qkv, const int* __restrict__ pos_ids,
                                  const float2* __restrict__ tab){
  const float QS = 0.08838834764831845f * 1.4426950408889634f;
  int t = blockIdx.x;
  int pos = pos_ids[t];
  const float2* tb = tab + pos * 64;
  u16* row = qkv + (size_t)t * QKVW_;
  for (int it = threadIdx.x; it < (H_ + HKV_) * 64; it += 256){
    int hh = it >> 6, p = it & 63;
    int base = (hh < H_) ? hh * D_ : HID_ + (hh - H_) * D_;
    float sc = (hh < H_) ? QS : 1.0f;
    float x1 = bf2f(row[base + p]);
    float x2 = bf2f(row[base + 64 + p]);
    float2 cs = tb[p];
    row[base + p]      = f2bf((x1 * cs.x - x2 * cs.y) * sc);
    row[base + 64 + p] = f2bf((x2 * cs.x + x1 * cs.y) * sc);
  }
}

// ---------------- bf16 GEMM, 256x256 tile, BK=64, 8 waves, 8-phase-style ----------------
// C[M][N] = A[M][K] * B[N][K]^T.  CF==0: bf16 out, CF==1: fp32 out.
#define MFMA_(a, b, c) __builtin_amdgcn_mfma_f32_16x16x32_bf16((a), (b), (c), 0, 0, 0)

template<int CF>
__global__ __launch_bounds__(512, 2) void gemm_bt(const u16* __restrict__ A, const u16* __restrict__ B,
                                                  void* __restrict__ Cv, int M, int N, int K, int nbn){
  __shared__ u16 As[2][256*64];
  __shared__ u16 Bs[2][256*64];
  const int tid = threadIdx.x;
  const int wave = tid >> 6, lane = tid & 63, lo = lane & 15, hi = lane >> 4;
  const int wr = wave >> 2, wc = wave & 3;
  const int slotBase = lo & 7;

  // T1: bijective XCD swizzle (nwg % 8 == 0 for all our launches)
  const int nwg = gridDim.x;
  const int bid = blockIdx.x;
  const int cpx = nwg >> 3;
  const int wg = (bid & 7) * cpx + (bid >> 3);
  const int bm = wg / nbn, bn = wg - bm * nbn;

  f32x4 acc[8][4] = {};

  // staging geometry: linear LDS dest (gload_lds), inverse-swizzled global source
  const int rbase = tid >> 3;                 // rows 0..63 (+p*64)
  const int cs = (tid & 7) ^ (rbase & 7);     // swizzled 8-elem slot
  const u16* ap = A + ((size_t)(bm*256 + rbase))*K + cs*8;
  const u16* bp = B + ((size_t)(bn*256 + rbase))*K + cs*8;
  const size_t pstride = (size_t)64 * K;
  u16* const dA = &As[0][0] + wave*512;
  u16* const dB = &Bs[0][0] + wave*512;

  // prologue: stage tile 0 into buf 0
  #pragma unroll
  for (int p = 0; p < 4; p++){
    gload16(ap + p*pstride, dA + p*4096);
    gload16(bp + p*pstride, dB + p*4096);
  }
  asm volatile("s_waitcnt vmcnt(0)" ::: "memory");
  __builtin_amdgcn_s_barrier();

  const int nk = K >> 6;
  for (int t = 0; t < nk; ++t){
    const int cur = t & 1, nxt = cur ^ 1;
    // issue ALL next-tile stages at phase 1 (target buffer's last reads completed
    // before the previous tile's end barrier -> no WAR race; 4 MFMA phases of cover)
    if (t + 1 < nk){
      const u16* a2 = ap + (size_t)(t+1)*64;
      const u16* b2 = bp + (size_t)(t+1)*64;
      u16* da = dA + nxt*16384;
      u16* db = dB + nxt*16384;
      #pragma unroll
      for (int p = 0; p < 4; p++){
        gload16(a2 + p*pstride, da + p*4096);
        gload16(b2 + p*pstride, db + p*4096);
      }
    }
    const u16* Ac = &As[cur][0];
    const u16* Bc = &Bs[cur][0];
    short8 av[8], bv[4];

    // ---- phase 1: load A-half0 + B-half0; compute quadrant (0,0) ----
    #pragma unroll
    for (int mt = 0; mt < 4; mt++)
      #pragma unroll
      for (int kk = 0; kk < 2; kk++)
        av[mt*2+kk] = *(const short8*)&Ac[(wr*128 + mt*16 + lo)*64 + (((kk*4+hi)^slotBase)*8)];
    #pragma unroll
    for (int nt = 0; nt < 2; nt++)
      #pragma unroll
      for (int kk = 0; kk < 2; kk++)
        bv[nt*2+kk] = *(const short8*)&Bc[(wc*64 + nt*16 + lo)*64 + (((kk*4+hi)^slotBase)*8)];
    __builtin_amdgcn_s_barrier();
    __builtin_amdgcn_s_setprio(1);
    #pragma unroll
    for (int mt = 0; mt < 4; mt++)
      #pragma unroll
      for (int nt = 0; nt < 2; nt++)
        #pragma unroll
        for (int kk = 0; kk < 2; kk++)
          acc[mt][nt] = MFMA_(av[mt*2+kk], bv[nt*2+kk], acc[mt][nt]);
    __builtin_amdgcn_s_setprio(0);
    __builtin_amdgcn_s_barrier();

    // ---- phase 2: load B-half1; compute quadrant (0,1) ----
    #pragma unroll
    for (int nt = 0; nt < 2; nt++)
      #pragma unroll
      for (int kk = 0; kk < 2; kk++)
        bv[nt*2+kk] = *(const short8*)&Bc[(wc*64 + 32 + nt*16 + lo)*64 + (((kk*4+hi)^slotBase)*8)];
    __builtin_amdgcn_s_barrier();
    __builtin_amdgcn_s_setprio(1);
    #pragma unroll
    for (int mt = 0; mt < 4; mt++)
      #pragma unroll
      for (int nt = 0; nt < 2; nt++)
        #pragma unroll
        for (int kk = 0; kk < 2; kk++)
          acc[mt][2+nt] = MFMA_(av[mt*2+kk], bv[nt*2+kk], acc[mt][2+nt]);
    __builtin_amdgcn_s_setprio(0);
    __builtin_amdgcn_s_barrier();

    // ---- phase 3: load A-half1; compute quadrant (1,1) ----
    #pragma unroll
    for (int mt = 0; mt < 4; mt++)
      #pragma unroll
      for (int kk = 0; kk < 2; kk++)
        av[mt*2+kk] = *(const short8*)&Ac[(wr*128 + 64 + mt*16 + lo)*64 + (((kk*4+hi)^slotBase)*8)];
    __builtin_amdgcn_s_barrier();
    __builtin_amdgcn_s_setprio(1);
    #pragma unroll
    for (int mt = 0; mt < 4; mt++)
      #pragma unroll
      for (int nt = 0; nt < 2; nt++)
        #pragma unroll
        for (int kk = 0; kk < 2; kk++)
          acc[4+mt][2+nt] = MFMA_(av[mt*2+kk], bv[nt*2+kk], acc[4+mt][2+nt]);
    __builtin_amdgcn_s_setprio(0);
    __builtin_amdgcn_s_barrier();

    // ---- phase 4: re-load B-half0; compute quadrant (1,0) ----
    #pragma unroll
    for (int nt = 0; nt < 2; nt++)
      #pragma unroll
      for (int kk = 0; kk < 2; kk++)
        bv[nt*2+kk] = *(const short8*)&Bc[(wc*64 + nt*16 + lo)*64 + (((kk*4+hi)^slotBase)*8)];
    __builtin_amdgcn_s_barrier();
    __builtin_amdgcn_s_setprio(1);
    #pragma unroll
    for (int mt = 0; mt < 4; mt++)
      #pragma unroll
      for (int nt = 0; nt < 2; nt++)
        #pragma unroll
        for (int kk = 0; kk < 2; kk++)
          acc[4+mt][nt] = MFMA_(av[mt*2+kk], bv[nt*2+kk], acc[4+mt][nt]);
    __builtin_amdgcn_s_setprio(0);
    // end of K-tile: single counted drain (RAW for next tile's buffer)
    asm volatile("s_waitcnt vmcnt(0)" ::: "memory");
    __builtin_amdgcn_s_barrier();
  }

  #pragma unroll
  for (int i = 0; i < 8; i++){
    int row = bm*256 + wr*128 + (i>>2)*64 + (i&3)*16 + 4*hi;
    #pragma unroll
    for (int j = 0; j < 4; j++){
      int col = bn*256 + wc*64 + (j>>1)*32 + (j&1)*16 + lo;
      #pragma unroll
      for (int r = 0; r < 4; r++){
        if (CF == 0) ((u16*)Cv)[(size_t)(row + r)*N + col] = f2bf(acc[i][j][r]);
        else         ((float*)Cv)[(size_t)(row + r)*N + col] = acc[i][j][r];
      }
    }
  }
}

// ---------------- fused windowed-causal GQA flash attention ----------------
__global__ __launch_bounds__(256) void attn_kernel(const u16* __restrict__ qkv, u16* __restrict__ out,
                                                   const int* __restrict__ winp){
  const int h = blockIdx.x, qt = blockIdx.y, b = blockIdx.z;
  const int hkv = h >> 2;
  const int q0 = qt * 64;
  const int tid = threadIdx.x, wave = tid >> 6, lane = tid & 63;
  const int lo = lane & 15, hi = lane >> 4;
  const int win = winp[0];

  __shared__ u16 Ks[2][64*128];
  __shared__ uint32_t VT[2][128*36];
  __shared__ u16 Pl[4][16*72];

  const int qw = q0 + wave*16;
  short8 qf[4];
  {
    const u16* qp = qkv + (size_t)(b*S_ + qw + lo)*QKVW_ + h*D_ + hi*8;
    #pragma unroll
    for (int c = 0; c < 4; c++) qf[c] = *(const short8*)(qp + c*32);
  }

  f32x4 accO[8] = {};
  float m_r = -3.0e38f, l_r = 0.0f;

  int js = q0 - (win - 1); if (js < 0) js = 0; js &= ~63;
  const int nt = (q0 + 64 - js) >> 6;

  const u16* Kg = qkv + (size_t)HID_ + hkv*D_;
  const u16* Vg = qkv + (size_t)HID_ + HKV_*D_ + hkv*D_;
  const int jp = tid & 31, d0 = (tid >> 5) * 16;

  const u16* ksrc[4];
  #pragma unroll
  for (int p = 0; p < 4; p++){
    int e = p*256 + tid;
    int row = e >> 4;
    int ss = (e & 15) ^ (row & 7);
    ksrc[p] = Kg + (size_t)(b*S_ + js + row)*QKVW_ + ss*8;
  }
  const u16* vsrc = Vg + (size_t)(b*S_ + js + 2*jp)*QKVW_ + d0;

  u16x8 vr0, vr1, vr2, vr3;
  {
    #pragma unroll
    for (int p = 0; p < 4; p++) gload16(ksrc[p], &Ks[0][p*2048 + wave*512]);
    vr0 = *(const u16x8*)(vsrc);
    vr1 = *(const u16x8*)(vsrc + 8);
    vr2 = *(const u16x8*)(vsrc + QKVW_);
    vr3 = *(const u16x8*)(vsrc + QKVW_ + 8);
    #pragma unroll
    for (int i = 0; i < 8; i++){
      VT[0][(d0+i)*36 + jp]   = (uint32_t)vr0[i] | ((uint32_t)vr2[i] << 16);
      VT[0][(d0+8+i)*36 + jp] = (uint32_t)vr1[i] | ((uint32_t)vr3[i] << 16);
    }
  }
  __syncthreads();

  for (int t = 0; t < nt; t++){
    const int jc = js + t*64;
    const int cur = t & 1, nxt = cur ^ 1;
    const bool more = (t + 1 < nt);
    if (more){
      const size_t adv = (size_t)(t+1) * 64 * QKVW_;
      #pragma unroll
      for (int p = 0; p < 4; p++) gload16(ksrc[p] + adv, &Ks[nxt][p*2048 + wave*512]);
      const u16* vp = vsrc + adv;
      vr0 = *(const u16x8*)(vp);
      vr1 = *(const u16x8*)(vp + 8);
      vr2 = *(const u16x8*)(vp + QKVW_);
      vr3 = *(const u16x8*)(vp + QKVW_ + 8);
    }
    if (jc <= qw + 15 && jc + 63 >= qw - win + 1){
      f32x4 s[4] = {};
      #pragma unroll
      for (int jt = 0; jt < 4; jt++)
        #pragma unroll
        for (int c = 0; c < 4; c++){
          short8 kf = *(const short8*)&Ks[cur][(jt*16+lo)*128 + (((c*4+hi) ^ (lo & 7)) * 8)];
          s[jt] = __builtin_amdgcn_mfma_f32_16x16x32_bf16(kf, qf[c], s[jt], 0, 0, 0);
        }
      const int qa = qw + lo;
      const bool fullv = (jc + 63 <= qw) && (jc >= qw + 16 - win);
      if (!fullv){
        #pragma unroll
        for (int jt = 0; jt < 4; jt++)
          #pragma unroll
          for (int r = 0; r < 4; r++){
            int j = jc + jt*16 + 4*hi + r;
            if (j > qa || qa - j >= win) s[jt][r] = -3.0e38f;
          }
      }
      float mx = s[0][0];
      #pragma unroll
      for (int jt = 0; jt < 4; jt++)
        #pragma unroll
        for (int r = 0; r < 4; r++) mx = fmaxf(mx, s[jt][r]);
      mx = fmaxf(mx, __shfl_xor(mx, 16));
      mx = fmaxf(mx, __shfl_xor(mx, 32));
      if (__any(mx > m_r + 8.0f)){
        float mn = fmaxf(m_r, mx);
        float al = exp2f(m_r - mn);
        m_r = mn; l_r *= al;
        float a0 = __shfl(al, 4*hi+0), a1 = __shfl(al, 4*hi+1);
        float a2 = __shfl(al, 4*hi+2), a3 = __shfl(al, 4*hi+3);
        #pragma unroll
        for (int dt = 0; dt < 8; dt++){
          accO[dt][0] *= a0; accO[dt][1] *= a1;
          accO[dt][2] *= a2; accO[dt][3] *= a3;
        }
      }
      float ps = 0.f;
      #pragma unroll
      for (int jt = 0; jt < 4; jt++){
        float p0, p1, p2, p3;
        if (fullv){
          p0 = exp2f(s[jt][0] - m_r); p1 = exp2f(s[jt][1] - m_r);
          p2 = exp2f(s[jt][2] - m_r); p3 = exp2f(s[jt][3] - m_r);
        } else {
          p0 = s[jt][0] > -1e37f ? exp2f(s[jt][0] - m_r) : 0.f;
          p1 = s[jt][1] > -1e37f ? exp2f(s[jt][1] - m_r) : 0.f;
          p2 = s[jt][2] > -1e37f ? exp2f(s[jt][2] - m_r) : 0.f;
          p3 = s[jt][3] > -1e37f ? exp2f(s[jt][3] - m_r) : 0.f;
        }
        ps += (p0 + p1) + (p2 + p3);
        uint32_t w0 = (uint32_t)bfc(p0) | ((uint32_t)bfc(p1) << 16);
        uint32_t w1 = (uint32_t)bfc(p2) | ((uint32_t)bfc(p3) << 16);
        *(uint64_t*)&Pl[wave][lo*72 + jt*16 + 4*hi] = (uint64_t)w0 | ((uint64_t)w1 << 32);
      }
      ps += __shfl_xor(ps, 16);
      ps += __shfl_xor(ps, 32);
      l_r += ps;
      short8 pa0 = *(const short8*)&Pl[wave][lo*72 + hi*8];
      short8 pa1 = *(const short8*)&Pl[wave][lo*72 + 32 + hi*8];
      const u16* VT16 = (const u16*)&VT[cur][0];
      #pragma unroll
      for (int dt = 0; dt < 8; dt++){
        short8 vf0 = *(const short8*)&VT16[(dt*16+lo)*72 + hi*8];
        short8 vf1 = *(const short8*)&VT16[(dt*16+lo)*72 + 32 + hi*8];
        accO[dt] = __builtin_amdgcn_mfma_f32_16x16x32_bf16(pa0, vf0, accO[dt], 0, 0, 0);
        accO[dt] = __builtin_amdgcn_mfma_f32_16x16x32_bf16(pa1, vf1, accO[dt], 0, 0, 0);
      }
    }
    if (more){
      #pragma unroll
      for (int i = 0; i < 8; i++){
        VT[nxt][(d0+i)*36 + jp]   = (uint32_t)vr0[i] | ((uint32_t)vr2[i] << 16);
        VT[nxt][(d0+8+i)*36 + jp] = (uint32_t)vr1[i] | ((uint32_t)vr3[i] << 16);
      }
      __syncthreads();
    }
  }
  #pragma unroll
  for (int r = 0; r < 4; r++){
    float lr = __shfl(l_r, 4*hi + r);
    float invl = 1.0f / lr;
    int trow = b*S_ + qw + 4*hi + r;
    #pragma unroll
    for (int dt = 0; dt < 8; dt++)
      out[(size_t)trow*HID_ + h*D_ + dt*16 + lo] = f2bf(accO[dt][r] * invl);
  }
}

extern "C" void kernel_launch(void* const* d_in, const int* in_sizes, int n_in,
                              void* d_out, int out_size, void* d_ws, size_t ws_size,
                              hipStream_t stream) {
  const float* hs   = (const float*)d_in[0];
  const float* wqkv = (const float*)d_in[1];
  const float* wo   = (const float*)d_in[2];
  const int* pos  = (const int*)d_in[5];
  const int* winp = (const int*)d_in[7];
  float* out = (float*)d_out;

  u16* hsb = (u16*)d_ws;
  u16* wqb = hsb + (size_t)HID_*HID_;
  u16* wob = wqb + (size_t)QKVW_*HID_;
  u16* qkv = wob + (size_t)HID_*HID_;
  u16* att = qkv + (size_t)(B_*S_)*QKVW_;
  float2* tab = (float2*)(att + (size_t)(B_*S_)*HID_);

  cvt_kernel<<<2048, 256, 0, stream>>>(hs,   hsb, HID_*HID_/4);
  cvt_kernel<<<2048, 256, 0, stream>>>(wqkv, wqb, QKVW_*HID_/4);
  cvt_kernel<<<2048, 256, 0, stream>>>(wo,   wob, HID_*HID_/4);
  rope_table_kernel<<<(S_*64 + 255)/256, 256, 0, stream>>>(tab);
  gemm_bt<0><<<(B_*S_/256)*(QKVW_/256), 512, 0, stream>>>(hsb, wqb, (void*)qkv, B_*S_, QKVW_, HID_, QKVW_/256);
  rope_apply_kernel<<<B_*S_, 256, 0, stream>>>(qkv, pos, tab);
  attn_kernel<<<dim3(H_, S_/64, B_), 256, 0, stream>>>(qkv, att, winp);
  gemm_bt<1><<<(B_*S_/256)*(HID_/256), 512, 0, stream>>>(att, wob, (void*)out, B_*S_, HID_, HID_, HID_/256);
}

// Round 4
// 576.551 us; speedup vs baseline: 1.1993x; 1.1993x over previous
//
#include <hip/hip_runtime.h>
#include <hip/hip_bf16.h>
#include <stdint.h>

typedef unsigned short u16;
typedef __attribute__((ext_vector_type(8))) short short8;
typedef __attribute__((ext_vector_type(8))) unsigned short u16x8;
typedef __attribute__((ext_vector_type(4))) float f32x4;

#define B_    2
#define S_    2048
#define H_    32
#define HKV_  8
#define D_    128
#define HID_  4096
#define QKVW_ 6144

__device__ __forceinline__ u16 f2bf(float f){
  uint32_t b = __builtin_bit_cast(uint32_t, f);
  b += 0x7FFFu + ((b >> 16) & 1u);
  return (u16)(b >> 16);
}
__device__ __forceinline__ float bf2f(u16 h){
  uint32_t b = ((uint32_t)h) << 16;
  return __builtin_bit_cast(float, b);
}
__device__ __forceinline__ u16 bfc(float f){
  __hip_bfloat16 h = __float2bfloat16(f);
  return __builtin_bit_cast(u16, h);
}

__device__ __forceinline__ void gload16(const u16* g, u16* l){
  __builtin_amdgcn_global_load_lds((const __attribute__((address_space(1))) void*)g,
                                   (__attribute__((address_space(3))) void*)l, 16, 0, 0);
}

// ---------------- fp32 -> bf16 convert ----------------
__global__ void cvt_kernel(const float* __restrict__ src, u16* __restrict__ dst, int n4){
  int i = blockIdx.x * blockDim.x + threadIdx.x;
  int stride = gridDim.x * blockDim.x;
  for (; i < n4; i += stride){
    float4 v = reinterpret_cast<const float4*>(src)[i];
    union { u16 u[4]; unsigned long long ll; } o;
    o.u[0] = f2bf(v.x); o.u[1] = f2bf(v.y); o.u[2] = f2bf(v.z); o.u[3] = f2bf(v.w);
    reinterpret_cast<unsigned long long*>(dst)[i] = o.ll;
  }
}

// ---------------- RoPE table ----------------
__global__ void rope_table_kernel(float2* __restrict__ tab){
  int idx = blockIdx.x * blockDim.x + threadIdx.x;
  if (idx >= S_ * 64) return;
  int pos = idx >> 6, p = idx & 63;
  float inv = powf(10000.0f, -(float)p / 64.0f);
  float ang = (float)pos * inv;
  tab[idx] = make_float2(cosf(ang), sinf(ang));
}

// ---------------- RoPE apply ----------------
__global__ void rope_apply_kernel(u16* __restrict__ qkv, const int* __restrict__ pos_ids,
                                  const float2* __restrict__ tab){
  const float QS = 0.08838834764831845f * 1.4426950408889634f;
  int t = blockIdx.x;
  int pos = pos_ids[t];
  const float2* tb = tab + pos * 64;
  u16* row = qkv + (size_t)t * QKVW_;
  for (int it = threadIdx.x; it < (H_ + HKV_) * 64; it += 256){
    int hh = it >> 6, p = it & 63;
    int base = (hh < H_) ? hh * D_ : HID_ + (hh - H_) * D_;
    float sc = (hh < H_) ? QS : 1.0f;
    float x1 = bf2f(row[base + p]);
    float x2 = bf2f(row[base + 64 + p]);
    float2 cs = tb[p];
    row[base + p]      = f2bf((x1 * cs.x - x2 * cs.y) * sc);
    row[base + 64 + p] = f2bf((x2 * cs.x + x1 * cs.y) * sc);
  }
}

#define MFMA_(a, b, c) __builtin_amdgcn_mfma_f32_16x16x32_bf16((a), (b), (c), 0, 0, 0)

// ---------------- 128x128 GEMM (proven 880 TF structure): C = A * B^T, bf16 out ----------------
__global__ __launch_bounds__(256) void gemm128(const u16* __restrict__ A, const u16* __restrict__ B,
                                               u16* __restrict__ C, int M, int N, int K){
  __shared__ u16 As[128*64];
  __shared__ u16 Bs[128*64];
  const int tid  = threadIdx.x;
  const int wave = tid >> 6, lane = tid & 63;
  const int hi = lane >> 4, lo = lane & 15;
  const int bn = blockIdx.x, bm = blockIdx.y;
  const int wm = (wave >> 1) * 64, wn = (wave & 1) * 64;
  f32x4 acc[4][4] = {};

  const u16* ap[4]; const u16* bp[4];
  u16* lA[4]; u16* lB[4];
  #pragma unroll
  for (int p = 0; p < 4; p++){
    int e   = p*2048 + wave*512 + lane*8;
    int row = e >> 6;
    int cs  = ((e >> 3) & 7) ^ (row & 7);
    ap[p] = A + (size_t)(bm*128 + row) * K + cs*8;
    bp[p] = B + (size_t)(bn*128 + row) * K + cs*8;
    lA[p] = &As[p*2048 + wave*512];
    lB[p] = &Bs[p*2048 + wave*512];
  }
  const int sw = lo & 7;
  const int nk = K >> 6;
  for (int t = 0; t < nk; t++){
    #pragma unroll
    for (int p = 0; p < 4; p++){
      gload16(ap[p], lA[p]);
      gload16(bp[p], lB[p]);
      ap[p] += 64; bp[p] += 64;
    }
    __syncthreads();
    #pragma unroll
    for (int kk = 0; kk < 2; kk++){
      short8 af[4], bf[4];
      int sz = ((kk*4 + hi) ^ sw) * 8;
      #pragma unroll
      for (int mt = 0; mt < 4; mt++) af[mt] = *(const short8*)&As[(wm + mt*16 + lo)*64 + sz];
      #pragma unroll
      for (int nt = 0; nt < 4; nt++) bf[nt] = *(const short8*)&Bs[(wn + nt*16 + lo)*64 + sz];
      #pragma unroll
      for (int mt = 0; mt < 4; mt++)
        #pragma unroll
        for (int nt = 0; nt < 4; nt++)
          acc[mt][nt] = MFMA_(af[mt], bf[nt], acc[mt][nt]);
    }
    __syncthreads();
  }
  #pragma unroll
  for (int mt = 0; mt < 4; mt++){
    int row = bm*128 + wm + mt*16 + 4*hi;
    #pragma unroll
    for (int nt = 0; nt < 4; nt++){
      int col = bn*128 + wn + nt*16 + lo;
      #pragma unroll
      for (int r = 0; r < 4; r++)
        C[(size_t)(row + r)*N + col] = f2bf(acc[mt][nt][r]);
    }
  }
}

// ---------------- 256x256 GEMM, counted-vmcnt prefetch, fp32 out ----------------
__global__ __launch_bounds__(512, 2) void gemm256(const u16* __restrict__ A, const u16* __restrict__ B,
                                                  float* __restrict__ C, int M, int N, int K, int nbn){
  __shared__ u16 As[2][256*64];
  __shared__ u16 Bs[2][256*64];
  const int tid = threadIdx.x;
  const int wave = tid >> 6, lane = tid & 63, lo = lane & 15, hi = lane >> 4;
  const int wr = wave >> 2, wc = wave & 3;
  const int slotBase = lo & 7;

  const int nwg = gridDim.x;
  const int bid = blockIdx.x;
  const int cpx = nwg >> 3;
  const int wg = (bid & 7) * cpx + (bid >> 3);
  const int bm = wg / nbn, bn = wg - bm * nbn;

  f32x4 acc[8][4] = {};

  const int rbase = tid >> 3;
  const int cs = (tid & 7) ^ (rbase & 7);
  const u16* ap = A + ((size_t)(bm*256 + rbase))*K + cs*8;
  const u16* bp = B + ((size_t)(bn*256 + rbase))*K + cs*8;
  const size_t pstride = (size_t)64 * K;
  u16* const dA = &As[0][0] + wave*512;
  u16* const dB = &Bs[0][0] + wave*512;

  // prologue: stage tile 0 into buf 0
  #pragma unroll
  for (int p = 0; p < 4; p++){
    gload16(ap + p*pstride, dA + p*4096);
    gload16(bp + p*pstride, dB + p*4096);
  }
  asm volatile("s_waitcnt vmcnt(0)" ::: "memory");
  __builtin_amdgcn_s_barrier();

  const int nk = K >> 6;
  for (int t = 0; t < nk; ++t){
    const int cur = t & 1, nxt = cur ^ 1;
    // counted-vmcnt prefetch: issue next tile's 8 loads FIRST, then wait only
    // for the oldest 8 (this tile's) -- new prefetch stays in flight.
    if (t + 1 < nk){
      const u16* a2 = ap + (size_t)(t+1)*64;
      const u16* b2 = bp + (size_t)(t+1)*64;
      u16* da = dA + nxt*16384;
      u16* db = dB + nxt*16384;
      #pragma unroll
      for (int p = 0; p < 4; p++){
        gload16(a2 + p*pstride, da + p*4096);
        gload16(b2 + p*pstride, db + p*4096);
      }
      asm volatile("s_waitcnt vmcnt(8)" ::: "memory");
    } else {
      asm volatile("s_waitcnt vmcnt(0)" ::: "memory");
    }
    __builtin_amdgcn_sched_barrier(0);
    __builtin_amdgcn_s_barrier();

    const u16* Ac = &As[cur][0];
    const u16* Bc = &Bs[cur][0];
    short8 av[8], bv0[4], bv[4];

    // ---- phase 1: A-half0 + B-half0 (kept for phase 4); quadrant (0,0) ----
    #pragma unroll
    for (int mt = 0; mt < 4; mt++)
      #pragma unroll
      for (int kk = 0; kk < 2; kk++)
        av[mt*2+kk] = *(const short8*)&Ac[(wr*128 + mt*16 + lo)*64 + (((kk*4+hi)^slotBase)*8)];
    #pragma unroll
    for (int nt = 0; nt < 2; nt++)
      #pragma unroll
      for (int kk = 0; kk < 2; kk++)
        bv0[nt*2+kk] = *(const short8*)&Bc[(wc*64 + nt*16 + lo)*64 + (((kk*4+hi)^slotBase)*8)];
    __builtin_amdgcn_s_barrier();
    __builtin_amdgcn_s_setprio(1);
    #pragma unroll
    for (int mt = 0; mt < 4; mt++)
      #pragma unroll
      for (int nt = 0; nt < 2; nt++)
        #pragma unroll
        for (int kk = 0; kk < 2; kk++)
          acc[mt][nt] = MFMA_(av[mt*2+kk], bv0[nt*2+kk], acc[mt][nt]);
    __builtin_amdgcn_s_setprio(0);
    __builtin_amdgcn_s_barrier();

    // ---- phase 2: B-half1; quadrant (0,1) ----
    #pragma unroll
    for (int nt = 0; nt < 2; nt++)
      #pragma unroll
      for (int kk = 0; kk < 2; kk++)
        bv[nt*2+kk] = *(const short8*)&Bc[(wc*64 + 32 + nt*16 + lo)*64 + (((kk*4+hi)^slotBase)*8)];
    __builtin_amdgcn_s_barrier();
    __builtin_amdgcn_s_setprio(1);
    #pragma unroll
    for (int mt = 0; mt < 4; mt++)
      #pragma unroll
      for (int nt = 0; nt < 2; nt++)
        #pragma unroll
        for (int kk = 0; kk < 2; kk++)
          acc[mt][2+nt] = MFMA_(av[mt*2+kk], bv[nt*2+kk], acc[mt][2+nt]);
    __builtin_amdgcn_s_setprio(0);
    __builtin_amdgcn_s_barrier();

    // ---- phase 3: A-half1; quadrant (1,1) ----
    #pragma unroll
    for (int mt = 0; mt < 4; mt++)
      #pragma unroll
      for (int kk = 0; kk < 2; kk++)
        av[mt*2+kk] = *(const short8*)&Ac[(wr*128 + 64 + mt*16 + lo)*64 + (((kk*4+hi)^slotBase)*8)];
    __builtin_amdgcn_s_barrier();
    __builtin_amdgcn_s_setprio(1);
    #pragma unroll
    for (int mt = 0; mt < 4; mt++)
      #pragma unroll
      for (int nt = 0; nt < 2; nt++)
        #pragma unroll
        for (int kk = 0; kk < 2; kk++)
          acc[4+mt][2+nt] = MFMA_(av[mt*2+kk], bv[nt*2+kk], acc[4+mt][2+nt]);
    __builtin_amdgcn_s_setprio(0);
    __builtin_amdgcn_s_barrier();

    // ---- phase 4: reuse bv0; quadrant (1,0) -- no ds_reads ----
    __builtin_amdgcn_s_setprio(1);
    #pragma unroll
    for (int mt = 0; mt < 4; mt++)
      #pragma unroll
      for (int nt = 0; nt < 2; nt++)
        #pragma unroll
        for (int kk = 0; kk < 2; kk++)
          acc[4+mt][nt] = MFMA_(av[mt*2+kk], bv0[nt*2+kk], acc[4+mt][nt]);
    __builtin_amdgcn_s_setprio(0);
    __builtin_amdgcn_s_barrier();
  }

  #pragma unroll
  for (int i = 0; i < 8; i++){
    int row = bm*256 + wr*128 + (i>>2)*64 + (i&3)*16 + 4*hi;
    #pragma unroll
    for (int j = 0; j < 4; j++){
      int col = bn*256 + wc*64 + (j>>1)*32 + (j&1)*16 + lo;
      #pragma unroll
      for (int r = 0; r < 4; r++)
        C[(size_t)(row + r)*N + col] = acc[i][j][r];
    }
  }
}

// ---------------- fused windowed-causal GQA flash attention ----------------
__global__ __launch_bounds__(256) void attn_kernel(const u16* __restrict__ qkv, u16* __restrict__ out,
                                                   const int* __restrict__ winp){
  const int h = blockIdx.x, qt = blockIdx.y, b = blockIdx.z;
  const int hkv = h >> 2;
  const int q0 = qt * 64;
  const int tid = threadIdx.x, wave = tid >> 6, lane = tid & 63;
  const int lo = lane & 15, hi = lane >> 4;
  const int win = winp[0];

  __shared__ u16 Ks[2][64*128];
  __shared__ uint32_t VT[2][128*36];
  __shared__ u16 Pl[4][16*72];

  const int qw = q0 + wave*16;
  short8 qf[4];
  {
    const u16* qp = qkv + (size_t)(b*S_ + qw + lo)*QKVW_ + h*D_ + hi*8;
    #pragma unroll
    for (int c = 0; c < 4; c++) qf[c] = *(const short8*)(qp + c*32);
  }

  f32x4 accO[8] = {};
  float m_r = -3.0e38f, l_r = 0.0f;

  int js = q0 - (win - 1); if (js < 0) js = 0; js &= ~63;
  const int nt = (q0 + 64 - js) >> 6;

  const u16* Kg = qkv + (size_t)HID_ + hkv*D_;
  const u16* Vg = qkv + (size_t)HID_ + HKV_*D_ + hkv*D_;
  const int jp = tid & 31, d0 = (tid >> 5) * 16;

  const u16* ksrc[4];
  #pragma unroll
  for (int p = 0; p < 4; p++){
    int e = p*256 + tid;
    int row = e >> 4;
    int ss = (e & 15) ^ (row & 7);
    ksrc[p] = Kg + (size_t)(b*S_ + js + row)*QKVW_ + ss*8;
  }
  const u16* vsrc = Vg + (size_t)(b*S_ + js + 2*jp)*QKVW_ + d0;

  u16x8 vr0, vr1, vr2, vr3;
  {
    #pragma unroll
    for (int p = 0; p < 4; p++) gload16(ksrc[p], &Ks[0][p*2048 + wave*512]);
    vr0 = *(const u16x8*)(vsrc);
    vr1 = *(const u16x8*)(vsrc + 8);
    vr2 = *(const u16x8*)(vsrc + QKVW_);
    vr3 = *(const u16x8*)(vsrc + QKVW_ + 8);
    #pragma unroll
    for (int i = 0; i < 8; i++){
      VT[0][(d0+i)*36 + jp]   = (uint32_t)vr0[i] | ((uint32_t)vr2[i] << 16);
      VT[0][(d0+8+i)*36 + jp] = (uint32_t)vr1[i] | ((uint32_t)vr3[i] << 16);
    }
  }
  __syncthreads();

  for (int t = 0; t < nt; t++){
    const int jc = js + t*64;
    const int cur = t & 1, nxt = cur ^ 1;
    const bool more = (t + 1 < nt);
    if (more){
      const size_t adv = (size_t)(t+1) * 64 * QKVW_;
      #pragma unroll
      for (int p = 0; p < 4; p++) gload16(ksrc[p] + adv, &Ks[nxt][p*2048 + wave*512]);
      const u16* vp = vsrc + adv;
      vr0 = *(const u16x8*)(vp);
      vr1 = *(const u16x8*)(vp + 8);
      vr2 = *(const u16x8*)(vp + QKVW_);
      vr3 = *(const u16x8*)(vp + QKVW_ + 8);
    }
    if (jc <= qw + 15 && jc + 63 >= qw - win + 1){
      f32x4 s[4] = {};
      __builtin_amdgcn_s_setprio(1);
      #pragma unroll
      for (int jt = 0; jt < 4; jt++)
        #pragma unroll
        for (int c = 0; c < 4; c++){
          short8 kf = *(const short8*)&Ks[cur][(jt*16+lo)*128 + (((c*4+hi) ^ (lo & 7)) * 8)];
          s[jt] = MFMA_(kf, qf[c], s[jt]);
        }
      __builtin_amdgcn_s_setprio(0);
      const int qa = qw + lo;
      const bool fullv = (jc + 63 <= qw) && (jc >= qw + 16 - win);
      if (!fullv){
        #pragma unroll
        for (int jt = 0; jt < 4; jt++)
          #pragma unroll
          for (int r = 0; r < 4; r++){
            int j = jc + jt*16 + 4*hi + r;
            if (j > qa || qa - j >= win) s[jt][r] = -3.0e38f;
          }
      }
      float mx = s[0][0];
      #pragma unroll
      for (int jt = 0; jt < 4; jt++)
        #pragma unroll
        for (int r = 0; r < 4; r++) mx = fmaxf(mx, s[jt][r]);
      mx = fmaxf(mx, __shfl_xor(mx, 16));
      mx = fmaxf(mx, __shfl_xor(mx, 32));
      if (__any(mx > m_r + 8.0f)){
        float mn = fmaxf(m_r, mx);
        float al = exp2f(m_r - mn);
        m_r = mn; l_r *= al;
        float a0 = __shfl(al, 4*hi+0), a1 = __shfl(al, 4*hi+1);
        float a2 = __shfl(al, 4*hi+2), a3 = __shfl(al, 4*hi+3);
        #pragma unroll
        for (int dt = 0; dt < 8; dt++){
          accO[dt][0] *= a0; accO[dt][1] *= a1;
          accO[dt][2] *= a2; accO[dt][3] *= a3;
        }
      }
      float ps = 0.f;
      #pragma unroll
      for (int jt = 0; jt < 4; jt++){
        float p0, p1, p2, p3;
        if (fullv){
          p0 = exp2f(s[jt][0] - m_r); p1 = exp2f(s[jt][1] - m_r);
          p2 = exp2f(s[jt][2] - m_r); p3 = exp2f(s[jt][3] - m_r);
        } else {
          p0 = s[jt][0] > -1e37f ? exp2f(s[jt][0] - m_r) : 0.f;
          p1 = s[jt][1] > -1e37f ? exp2f(s[jt][1] - m_r) : 0.f;
          p2 = s[jt][2] > -1e37f ? exp2f(s[jt][2] - m_r) : 0.f;
          p3 = s[jt][3] > -1e37f ? exp2f(s[jt][3] - m_r) : 0.f;
        }
        ps += (p0 + p1) + (p2 + p3);
        uint32_t w0 = (uint32_t)bfc(p0) | ((uint32_t)bfc(p1) << 16);
        uint32_t w1 = (uint32_t)bfc(p2) | ((uint32_t)bfc(p3) << 16);
        *(uint64_t*)&Pl[wave][lo*72 + jt*16 + 4*hi] = (uint64_t)w0 | ((uint64_t)w1 << 32);
      }
      ps += __shfl_xor(ps, 16);
      ps += __shfl_xor(ps, 32);
      l_r += ps;
      short8 pa0 = *(const short8*)&Pl[wave][lo*72 + hi*8];
      short8 pa1 = *(const short8*)&Pl[wave][lo*72 + 32 + hi*8];
      const u16* VT16 = (const u16*)&VT[cur][0];
      __builtin_amdgcn_s_setprio(1);
      #pragma unroll
      for (int dt = 0; dt < 8; dt++){
        short8 vf0 = *(const short8*)&VT16[(dt*16+lo)*72 + hi*8];
        short8 vf1 = *(const short8*)&VT16[(dt*16+lo)*72 + 32 + hi*8];
        accO[dt] = MFMA_(pa0, vf0, accO[dt]);
        accO[dt] = MFMA_(pa1, vf1, accO[dt]);
      }
      __builtin_amdgcn_s_setprio(0);
    }
    if (more){
      #pragma unroll
      for (int i = 0; i < 8; i++){
        VT[nxt][(d0+i)*36 + jp]   = (uint32_t)vr0[i] | ((uint32_t)vr2[i] << 16);
        VT[nxt][(d0+8+i)*36 + jp] = (uint32_t)vr1[i] | ((uint32_t)vr3[i] << 16);
      }
      __syncthreads();
    }
  }
  #pragma unroll
  for (int r = 0; r < 4; r++){
    float lr = __shfl(l_r, 4*hi + r);
    float invl = 1.0f / lr;
    int trow = b*S_ + qw + 4*hi + r;
    #pragma unroll
    for (int dt = 0; dt < 8; dt++)
      out[(size_t)trow*HID_ + h*D_ + dt*16 + lo] = f2bf(accO[dt][r] * invl);
  }
}

extern "C" void kernel_launch(void* const* d_in, const int* in_sizes, int n_in,
                              void* d_out, int out_size, void* d_ws, size_t ws_size,
                              hipStream_t stream) {
  const float* hs   = (const float*)d_in[0];
  const float* wqkv = (const float*)d_in[1];
  const float* wo   = (const float*)d_in[2];
  const int* pos  = (const int*)d_in[5];
  const int* winp = (const int*)d_in[7];
  float* out = (float*)d_out;

  u16* hsb = (u16*)d_ws;
  u16* wqb = hsb + (size_t)HID_*HID_;
  u16* wob = wqb + (size_t)QKVW_*HID_;
  u16* qkv = wob + (size_t)HID_*HID_;
  u16* att = qkv + (size_t)(B_*S_)*QKVW_;
  float2* tab = (float2*)(att + (size_t)(B_*S_)*HID_);

  cvt_kernel<<<2048, 256, 0, stream>>>(hs,   hsb, HID_*HID_/4);
  cvt_kernel<<<2048, 256, 0, stream>>>(wqkv, wqb, QKVW_*HID_/4);
  cvt_kernel<<<2048, 256, 0, stream>>>(wo,   wob, HID_*HID_/4);
  rope_table_kernel<<<(S_*64 + 255)/256, 256, 0, stream>>>(tab);
  gemm128<<<dim3(QKVW_/128, (B_*S_)/128), 256, 0, stream>>>(hsb, wqb, qkv, B_*S_, QKVW_, HID_);
  rope_apply_kernel<<<B_*S_, 256, 0, stream>>>(qkv, pos, tab);
  attn_kernel<<<dim3(H_, S_/64, B_), 256, 0, stream>>>(qkv, att, winp);
  gemm256<<<(B_*S_/256)*(HID_/256), 512, 0, stream>>>(att, wob, out, B_*S_, HID_, HID_, HID_/256);
}